// Round 1
// baseline (187.457 us; speedup 1.0000x reference)
//
#include <hip/hip_runtime.h>
#include <hip/hip_bf16.h>

#define T_DIM 2048
#define B_DIM 64
#define H_DIM 256
#define A_DIM 256
#define NCH 16
#define TCH 128
#define NEG_INF -1e12f

typedef __attribute__((ext_vector_type(8))) short short8;
typedef __attribute__((ext_vector_type(4))) float f32x4;

__device__ __forceinline__ unsigned short f2bf(float x) {
    unsigned int u = __float_as_uint(x);
    u = (u + 0x7FFFu + ((u >> 16) & 1u)) >> 16;
    return (unsigned short)u;
}
__device__ __forceinline__ float bf2f(unsigned short x) {
    return __uint_as_float(((unsigned int)x) << 16);
}
__device__ __forceinline__ float fast_tanh(float x) {
    float e = __expf(2.0f * x);
    return 1.0f - 2.0f / (e + 1.0f);
}
__device__ __forceinline__ float fast_sigmoid(float x) {
    return 1.0f / (1.0f + __expf(-x));
}

// K0: weight transposes / bf16 conversion into workspace
__global__ void prep_kernel(const float* __restrict__ W_a1,
                            const float* __restrict__ W_ih,
                            const float* __restrict__ W_hh,
                            unsigned short* __restrict__ WmT,
                            float* __restrict__ W_ihT,
                            float* __restrict__ W_hhT) {
    int idx = blockIdx.x * blockDim.x + threadIdx.x;
    if (idx < 65536) {
        int k = idx >> 8, a = idx & 255;
        WmT[a * 256 + k] = f2bf(W_a1[(512 + k) * 256 + a]);   // WmT[a][k] = W_a1[512+k][a]
    } else if (idx < 65536 + 393216) {
        int i = idx - 65536;
        int j = i % 768, k = i / 768;
        W_ihT[k * 768 + j] = W_ih[j * 512 + k];
    } else if (idx < 65536 + 393216 + 196608) {
        int i = idx - 65536 - 393216;
        int j = i % 768, k = i / 768;
        W_hhT[k * 768 + j] = W_hh[j * 256 + k];
    }
}

// K1: qs[b][a] = [input,state] @ W_a1[:512]
__global__ void qs_kernel(const float* __restrict__ input,
                          const float* __restrict__ state,
                          const float* __restrict__ W_a1,
                          float* __restrict__ qs) {
    __shared__ float cat[512];
    int b = blockIdx.x, a = threadIdx.x;
    cat[a] = input[b * 256 + a];
    cat[a + 256] = state[b * 256 + a];
    __syncthreads();
    float s = 0.f;
    #pragma unroll 8
    for (int k = 0; k < 512; ++k) s += cat[k] * W_a1[k * 256 + a];
    qs[b * 256 + a] = s;
}

// K2: fused logits-MLP (MFMA) + chunk-local softmax partials + weighted accum.
// grid (B, NCH), block 256 (4 waves). Each wave computes all 128 rows x its
// 64-col block of mp = mem_slab @ Wm; epilogue reduces tanh()*w2 to logits.
__global__ __launch_bounds__(256) void attn_kernel(
    const float* __restrict__ memory, const int* __restrict__ mask,
    const unsigned short* __restrict__ WmT,
    const float* __restrict__ qs, const float* __restrict__ w_a2,
    float* __restrict__ part_m, float* __restrict__ part_l,
    float* __restrict__ part_acc)
{
    extern __shared__ char smem[];
    unsigned short* slab = (unsigned short*)smem;        // [128][256] bf16, XOR-swizzled (64KB)
    float* lpart = (float*)(smem + 65536);               // [4][128] per-wave logit partials
    float* pbuf  = lpart + 512;                          // [128] logits -> p
    float* redm  = pbuf + 128;                           // [2] m, l

    int b = blockIdx.x, ch = blockIdx.y;
    int tid = threadIdx.x;
    int lane = tid & 63, w = tid >> 6;
    int lr = lane & 15, lh = lane >> 4;
    int t0 = ch * TCH;
    const float* mbase = memory + (size_t)t0 * (B_DIM * H_DIM) + b * H_DIM;

    // ---- stage slab: f32 -> bf16, swizzle byte ^= ((row&7)<<4) ----
    #pragma unroll
    for (int i = 0; i < 32; ++i) {
        int idx4 = i * 256 + tid;
        int t = idx4 >> 6, h4 = idx4 & 63;
        const float4* rp = (const float4*)(mbase + (size_t)t * (B_DIM * H_DIM));
        float4 v = rp[h4];
        ushort4 o;
        o.x = f2bf(v.x); o.y = f2bf(v.y); o.z = f2bf(v.z); o.w = f2bf(v.w);
        int sw = ((h4 * 8) ^ ((t & 7) << 4)) >> 1;
        *(ushort4*)(slab + t * 256 + sw) = o;
    }
    __syncthreads();

    // ---- MFMA: C[row=t_local][col=a], wave owns cols wn0..wn0+63 ----
    int wn0 = w * 64;
    f32x4 acc[8][4];
    #pragma unroll
    for (int mf = 0; mf < 8; ++mf)
        #pragma unroll
        for (int n = 0; n < 4; ++n)
            acc[mf][n] = (f32x4){0.f, 0.f, 0.f, 0.f};

    #pragma unroll
    for (int kk = 0; kk < 8; ++kk) {
        int kbyte = kk * 64 + lh * 16;              // (kk*32 + lh*8) bf16 * 2B
        short8 afr[8];
        #pragma unroll
        for (int mf = 0; mf < 8; ++mf) {
            int row = mf * 16 + lr;
            int sw = kbyte ^ ((row & 7) << 4);
            afr[mf] = *(const short8*)(slab + row * 256 + (sw >> 1));
        }
        #pragma unroll
        for (int n = 0; n < 4; ++n) {
            int col = wn0 + n * 16 + lr;
            short8 bfr = *(const short8*)(WmT + col * 256 + kk * 32 + lh * 8);
            #pragma unroll
            for (int mf = 0; mf < 8; ++mf)
                acc[mf][n] = __builtin_amdgcn_mfma_f32_16x16x32_bf16(afr[mf], bfr, acc[mf][n], 0, 0, 0);
        }
    }

    // ---- epilogue: logit[row] = sum_a w2[a]*tanh(qs[b,a] + mp[row,a]) ----
    float qv[4], wv[4];
    #pragma unroll
    for (int n = 0; n < 4; ++n) {
        int col = wn0 + n * 16 + lr;
        qv[n] = qs[b * 256 + col];
        wv[n] = w_a2[col];
    }
    #pragma unroll
    for (int mf = 0; mf < 8; ++mf) {
        #pragma unroll
        for (int r = 0; r < 4; ++r) {
            float s = 0.f;
            #pragma unroll
            for (int n = 0; n < 4; ++n)
                s += wv[n] * fast_tanh(qv[n] + acc[mf][n][r]);
            s += __shfl_xor(s, 1);
            s += __shfl_xor(s, 2);
            s += __shfl_xor(s, 4);
            s += __shfl_xor(s, 8);
            if (lr == 0) lpart[w * 128 + mf * 16 + lh * 4 + r] = s;  // C row = (l>>4)*4+r
        }
    }
    __syncthreads();

    // ---- combine wave partials, mask ----
    if (tid < 128) {
        float lg = lpart[tid] + lpart[128 + tid] + lpart[256 + tid] + lpart[384 + tid];
        int t = t0 + tid;
        lg = mask[t * B_DIM + b] ? lg : NEG_INF;
        pbuf[tid] = lg;
    }
    __syncthreads();

    // ---- chunk-local softmax (wave 0) ----
    if (w == 0) {
        float a0 = pbuf[lane], a1 = pbuf[64 + lane];
        float mx = fmaxf(a0, a1);
        #pragma unroll
        for (int d = 1; d < 64; d <<= 1) mx = fmaxf(mx, __shfl_xor(mx, d));
        float e0 = __expf(a0 - mx), e1 = __expf(a1 - mx);
        float sm = e0 + e1;
        #pragma unroll
        for (int d = 1; d < 64; d <<= 1) sm += __shfl_xor(sm, d);
        pbuf[lane] = e0; pbuf[64 + lane] = e1;
        if (lane == 0) { redm[0] = mx; redm[1] = sm; }
    }
    __syncthreads();

    // ---- weighted accumulation: acc[h] = sum_t p[t]*mem[t,h] (from LDS) ----
    float av = 0.f;
    int h = tid;
    #pragma unroll 8
    for (int t = 0; t < TCH; ++t) {
        int sw = ((h * 2) ^ ((t & 7) << 4)) >> 1;
        av += pbuf[t] * bf2f(slab[t * 256 + sw]);
    }
    int pidx = ch * B_DIM + b;
    part_acc[(size_t)pidx * 256 + h] = av;
    if (tid == 0) { part_m[pidx] = redm[0]; part_l[pidx] = redm[1]; }
}

// K3: merge chunk partials -> attn[b][h]
__global__ void merge_kernel(const float* __restrict__ part_m,
                             const float* __restrict__ part_l,
                             const float* __restrict__ part_acc,
                             float* __restrict__ attn) {
    int b = blockIdx.x, h = threadIdx.x;
    float M = -3.4e38f;
    #pragma unroll
    for (int c = 0; c < NCH; ++c) M = fmaxf(M, part_m[c * 64 + b]);
    float L = 0.f, s = 0.f;
    #pragma unroll
    for (int c = 0; c < NCH; ++c) {
        float sc = __expf(part_m[c * 64 + b] - M);
        L += part_l[c * 64 + b] * sc;
        s += sc * part_acc[(size_t)(c * 64 + b) * 256 + h];
    }
    attn[b * 256 + h] = s / L;
}

// K4: gated = new_input * sigmoid(new_input @ W_gate)
__global__ void gate_kernel(const float* __restrict__ input,
                            const float* __restrict__ attn,
                            const float* __restrict__ W_gate,
                            float* __restrict__ gated) {
    __shared__ float ni[512];
    int b = blockIdx.x, j = threadIdx.x;
    ni[j] = (j < 256) ? input[b * 256 + j] : attn[b * 256 + j - 256];
    __syncthreads();
    float s = 0.f;
    #pragma unroll 8
    for (int k = 0; k < 512; ++k) s += ni[k] * W_gate[k * 512 + j];
    gated[b * 512 + j] = ni[j] * fast_sigmoid(s);
}

// K5: GRU cell (torch gate order r,z,n)
__global__ void gru_kernel(const float* __restrict__ gated,
                           const float* __restrict__ state,
                           const float* __restrict__ W_ihT,
                           const float* __restrict__ W_hhT,
                           const float* __restrict__ b_ih,
                           const float* __restrict__ b_hh,
                           float* __restrict__ out) {
    __shared__ float g[512];
    __shared__ float st[256];
    int b = blockIdx.x, hh = threadIdx.x;
    g[hh] = gated[b * 512 + hh];
    g[hh + 256] = gated[b * 512 + 256 + hh];
    st[hh] = state[b * 256 + hh];
    __syncthreads();
    float ir = b_ih[hh], iz = b_ih[256 + hh], in_ = b_ih[512 + hh];
    #pragma unroll 4
    for (int k = 0; k < 512; ++k) {
        float gv = g[k];
        const float* Wk = W_ihT + k * 768;
        ir += gv * Wk[hh]; iz += gv * Wk[256 + hh]; in_ += gv * Wk[512 + hh];
    }
    float hr = b_hh[hh], hz = b_hh[256 + hh], hn = b_hh[512 + hh];
    #pragma unroll 4
    for (int k = 0; k < 256; ++k) {
        float sv = st[k];
        const float* Wk = W_hhT + k * 768;
        hr += sv * Wk[hh]; hz += sv * Wk[256 + hh]; hn += sv * Wk[512 + hh];
    }
    float r = fast_sigmoid(ir + hr);
    float z = fast_sigmoid(iz + hz);
    float n = fast_tanh(in_ + r * hn);
    out[b * 256 + hh] = (1.f - z) * n + z * st[hh];
}

extern "C" void kernel_launch(void* const* d_in, const int* in_sizes, int n_in,
                              void* d_out, int out_size, void* d_ws, size_t ws_size,
                              hipStream_t stream) {
    const float* input  = (const float*)d_in[0];
    const float* memory = (const float*)d_in[1];
    const int*   mask   = (const int*)d_in[2];
    const float* state  = (const float*)d_in[3];
    const float* W_a1   = (const float*)d_in[4];
    const float* w_a2   = (const float*)d_in[5];
    const float* W_gate = (const float*)d_in[6];
    const float* W_ih   = (const float*)d_in[7];
    const float* W_hh   = (const float*)d_in[8];
    const float* b_ih   = (const float*)d_in[9];
    const float* b_hh   = (const float*)d_in[10];
    float* out = (float*)d_out;

    char* ws = (char*)d_ws;
    unsigned short* WmT = (unsigned short*)(ws + 0);        // 131072 B
    float* W_ihT  = (float*)(ws + 131072);                  // 1572864 B
    float* W_hhT  = (float*)(ws + 1703936);                 // 786432 B
    float* qs     = (float*)(ws + 2490368);                 // 65536 B
    float* attn   = (float*)(ws + 2555904);                 // 65536 B
    float* gated  = (float*)(ws + 2621440);                 // 131072 B
    float* part_m = (float*)(ws + 2752512);                 // 4096 B
    float* part_l = (float*)(ws + 2756608);                 // 4096 B
    float* part_acc = (float*)(ws + 2760704);               // 1048576 B

    prep_kernel<<<2560, 256, 0, stream>>>(W_a1, W_ih, W_hh, WmT, W_ihT, W_hhT);
    qs_kernel<<<64, 256, 0, stream>>>(input, state, W_a1, qs);

    (void)hipFuncSetAttribute((const void*)attn_kernel,
                              hipFuncAttributeMaxDynamicSharedMemorySize, 68352);
    attn_kernel<<<dim3(B_DIM, NCH), 256, 68352, stream>>>(
        memory, mask, WmT, qs, w_a2, part_m, part_l, part_acc);

    merge_kernel<<<64, 256, 0, stream>>>(part_m, part_l, part_acc, attn);
    gate_kernel<<<64, 512, 0, stream>>>(input, attn, W_gate, gated);
    gru_kernel<<<64, 256, 0, stream>>>(gated, state, W_ihT, W_hhT, b_ih, b_hh, out);
}

// Round 2
// 186.459 us; speedup vs baseline: 1.0053x; 1.0053x over previous
//
#include <hip/hip_runtime.h>
#include <hip/hip_bf16.h>

#define T_DIM 2048
#define B_DIM 64
#define H_DIM 256
#define A_DIM 256
#define NCH 32
#define TCH 64
#define NEG_INF -1e12f

typedef __attribute__((ext_vector_type(8))) short short8;
typedef __attribute__((ext_vector_type(4))) float f32x4;

__device__ __forceinline__ unsigned short f2bf(float x) {
    unsigned int u = __float_as_uint(x);
    u = (u + 0x7FFFu + ((u >> 16) & 1u)) >> 16;
    return (unsigned short)u;
}
__device__ __forceinline__ float bf2f(unsigned short x) {
    return __uint_as_float(((unsigned int)x) << 16);
}
__device__ __forceinline__ float fast_tanh(float x) {
    float e = __expf(2.0f * x);
    return 1.0f - 2.0f / (e + 1.0f);
}
__device__ __forceinline__ float fast_sigmoid(float x) {
    return 1.0f / (1.0f + __expf(-x));
}

// K0: WmT[a][k] = bf16(W_a1[512+k][a])  (MFMA B-operand, K-contiguous)
__global__ void prep_wmt(const float* __restrict__ W_a1,
                         unsigned short* __restrict__ WmT) {
    int idx = blockIdx.x * blockDim.x + threadIdx.x;   // 65536
    int k = idx >> 8, a = idx & 255;
    WmT[a * 256 + k] = f2bf(W_a1[(512 + k) * 256 + a]);
}

// K1: qs[b][a] = [input,state] @ W_a1[:512]
// grid (8 a-tiles, 8 b-tiles), block 256: thread = (b-row 0..7, a-lane 0..31)
__global__ void qs_kernel(const float* __restrict__ input,
                          const float* __restrict__ state,
                          const float* __restrict__ W_a1,
                          float* __restrict__ qs) {
    __shared__ float cat[8][516];
    int a0 = blockIdx.x * 32, b0 = blockIdx.y * 8;
    int tid = threadIdx.x;
    #pragma unroll
    for (int i = 0; i < 16; ++i) {
        int idx = i * 256 + tid;
        int row = idx >> 9, k = idx & 511;
        cat[row][k] = (k < 256) ? input[(b0 + row) * 256 + k]
                                : state[(b0 + row) * 256 + k - 256];
    }
    __syncthreads();
    int a = a0 + (tid & 31), row = tid >> 5;
    float s = 0.f;
    #pragma unroll 8
    for (int k = 0; k < 512; ++k) s += cat[row][k] * W_a1[k * 256 + a];
    qs[(b0 + row) * 256 + a] = s;
}

// K2: fused logits-MLP (MFMA) + chunk softmax partials + weighted accum.
// grid (B, NCH), block 512 (8 waves); wave w owns 32 cols of A.
__global__ __launch_bounds__(512, 4) void attn_kernel(
    const float* __restrict__ memory, const int* __restrict__ mask,
    const unsigned short* __restrict__ WmT,
    const float* __restrict__ qs, const float* __restrict__ w_a2,
    float* __restrict__ part_m, float* __restrict__ part_l,
    float* __restrict__ part_acc)
{
    __shared__ unsigned short slab[TCH * 256];   // [64][256] bf16, XOR-swizzled
    __shared__ float lpart[8 * 64];
    __shared__ float pbuf[64];
    __shared__ float acc2[512];
    __shared__ float redm[2];

    int b = blockIdx.x, ch = blockIdx.y;
    int tid = threadIdx.x;
    int lane = tid & 63, w = tid >> 6;
    int lr = lane & 15, lh = lane >> 4;
    int t0 = ch * TCH;
    const float* mbase = memory + (size_t)t0 * (B_DIM * H_DIM) + b * H_DIM;

    // epilogue constants (issue loads early)
    int wn0 = w * 32;
    float qv[2], wv[2];
    #pragma unroll
    for (int n = 0; n < 2; ++n) {
        int col = wn0 + n * 16 + lr;
        qv[n] = qs[b * 256 + col];
        wv[n] = w_a2[col];
    }

    // ---- stage slab: f32 -> bf16, swizzle byte ^= ((row&7)<<4) ----
    #pragma unroll
    for (int i = 0; i < 8; ++i) {
        int idx4 = i * 512 + tid;
        int t = idx4 >> 6, h4 = idx4 & 63;
        const float4* rp = (const float4*)(mbase + (size_t)t * (B_DIM * H_DIM));
        float4 v = rp[h4];
        ushort4 o;
        o.x = f2bf(v.x); o.y = f2bf(v.y); o.z = f2bf(v.z); o.w = f2bf(v.w);
        int sw = ((h4 * 8) ^ ((t & 7) << 4)) >> 1;
        *(ushort4*)(slab + t * 256 + sw) = o;
    }
    __syncthreads();

    // ---- MFMA: mp[row=t_local][col=a], wave owns cols wn0..wn0+31 ----
    f32x4 acc[4][2];
    #pragma unroll
    for (int mf = 0; mf < 4; ++mf)
        #pragma unroll
        for (int n = 0; n < 2; ++n)
            acc[mf][n] = (f32x4){0.f, 0.f, 0.f, 0.f};

    #pragma unroll
    for (int kk = 0; kk < 8; ++kk) {
        int kbyte = kk * 64 + lh * 16;
        short8 afr[4];
        #pragma unroll
        for (int mf = 0; mf < 4; ++mf) {
            int row = mf * 16 + lr;
            int sw = kbyte ^ ((row & 7) << 4);
            afr[mf] = *(const short8*)(slab + row * 256 + (sw >> 1));
        }
        #pragma unroll
        for (int n = 0; n < 2; ++n) {
            int col = wn0 + n * 16 + lr;
            short8 bfr = *(const short8*)(WmT + col * 256 + kk * 32 + lh * 8);
            #pragma unroll
            for (int mf = 0; mf < 4; ++mf)
                acc[mf][n] = __builtin_amdgcn_mfma_f32_16x16x32_bf16(afr[mf], bfr, acc[mf][n], 0, 0, 0);
        }
    }

    // ---- epilogue: wave-partial logit[row] = sum_{cols} w2*tanh(qs+mp) ----
    #pragma unroll
    for (int mf = 0; mf < 4; ++mf) {
        #pragma unroll
        for (int r = 0; r < 4; ++r) {
            float s = 0.f;
            #pragma unroll
            for (int n = 0; n < 2; ++n)
                s += wv[n] * fast_tanh(qv[n] + acc[mf][n][r]);
            s += __shfl_xor(s, 1);
            s += __shfl_xor(s, 2);
            s += __shfl_xor(s, 4);
            s += __shfl_xor(s, 8);
            if (lr == 0) lpart[w * 64 + mf * 16 + lh * 4 + r] = s;
        }
    }
    __syncthreads();

    // ---- combine wave partials, mask ----
    if (tid < 64) {
        float lg = 0.f;
        #pragma unroll
        for (int ww = 0; ww < 8; ++ww) lg += lpart[ww * 64 + tid];
        int t = t0 + tid;
        pbuf[tid] = mask[t * B_DIM + b] ? lg : NEG_INF;
    }
    __syncthreads();

    // ---- chunk-local softmax (wave 0, 64 t-values) ----
    if (w == 0) {
        float a0 = pbuf[lane];
        float mx = a0;
        #pragma unroll
        for (int d = 1; d < 64; d <<= 1) mx = fmaxf(mx, __shfl_xor(mx, d));
        float e0 = __expf(a0 - mx);
        float sm = e0;
        #pragma unroll
        for (int d = 1; d < 64; d <<= 1) sm += __shfl_xor(sm, d);
        pbuf[lane] = e0;
        if (lane == 0) { redm[0] = mx; redm[1] = sm; }
    }
    __syncthreads();

    // ---- weighted accumulation: split t-range across 2 thread-halves ----
    int h = tid & 255, half = tid >> 8;
    float av = 0.f;
    #pragma unroll 8
    for (int ti = 0; ti < 32; ++ti) {
        int t = half * 32 + ti;
        int sw = ((h * 2) ^ ((t & 7) << 4)) >> 1;
        av += pbuf[t] * bf2f(slab[t * 256 + sw]);
    }
    acc2[half * 256 + h] = av;
    __syncthreads();
    int pidx = ch * B_DIM + b;
    if (tid < 256) part_acc[(size_t)pidx * 256 + tid] = acc2[tid] + acc2[256 + tid];
    if (tid == 0) { part_m[pidx] = redm[0]; part_l[pidx] = redm[1]; }
}

// K3: merge chunk partials -> attn[b][h]
__global__ void merge_kernel(const float* __restrict__ part_m,
                             const float* __restrict__ part_l,
                             const float* __restrict__ part_acc,
                             float* __restrict__ attn) {
    int b = blockIdx.x, h = threadIdx.x;
    float M = -3.4e38f;
    #pragma unroll
    for (int c = 0; c < NCH; ++c) M = fmaxf(M, part_m[c * 64 + b]);
    float L = 0.f, s = 0.f;
    #pragma unroll
    for (int c = 0; c < NCH; ++c) {
        float sc = __expf(part_m[c * 64 + b] - M);
        L += part_l[c * 64 + b] * sc;
        s += sc * part_acc[(size_t)(c * 64 + b) * 256 + h];
    }
    attn[b * 256 + h] = s / L;
}

// K4: gated = new_input * sigmoid(new_input @ W_gate)
// grid (16 j-tiles, 8 b-tiles), block 256
__global__ void gate_kernel(const float* __restrict__ input,
                            const float* __restrict__ attn,
                            const float* __restrict__ W_gate,
                            float* __restrict__ gated) {
    __shared__ float ni[8][516];
    int j0 = blockIdx.x * 32, b0 = blockIdx.y * 8;
    int tid = threadIdx.x;
    #pragma unroll
    for (int i = 0; i < 16; ++i) {
        int idx = i * 256 + tid;
        int row = idx >> 9, k = idx & 511;
        ni[row][k] = (k < 256) ? input[(b0 + row) * 256 + k]
                               : attn[(b0 + row) * 256 + k - 256];
    }
    __syncthreads();
    int j = j0 + (tid & 31), row = tid >> 5;
    float s = 0.f;
    #pragma unroll 8
    for (int k = 0; k < 512; ++k) s += ni[row][k] * W_gate[k * 512 + j];
    gated[(b0 + row) * 512 + j] = ni[row][j] * fast_sigmoid(s);
}

// K5: GRU cell. grid (8 h-tiles, 8 b-tiles), block 768:
// thread = (gate 0..2, b-row 0..7, h-lane 0..31); streams W rows contiguously.
__global__ void gru_kernel(const float* __restrict__ gated,
                           const float* __restrict__ state,
                           const float* __restrict__ W_ih,
                           const float* __restrict__ W_hh,
                           const float* __restrict__ b_ih,
                           const float* __restrict__ b_hh,
                           float* __restrict__ out) {
    __shared__ float g[8][516];
    __shared__ float st[8][260];
    __shared__ float xi[3 * 8 * 32];
    __shared__ float xh[3 * 8 * 32];
    int h0 = blockIdx.x * 32, b0 = blockIdx.y * 8;
    int tid = threadIdx.x;
    #pragma unroll
    for (int i = 0; i < 6; ++i) {
        int idx = i * 768 + tid;
        if (idx < 4096) {
            int row = idx >> 9, k = idx & 511;
            g[row][k] = gated[(b0 + row) * 512 + k];
        }
    }
    #pragma unroll
    for (int i = 0; i < 3; ++i) {
        int idx = i * 768 + tid;
        if (idx < 2048) {
            int row = idx >> 8, k = idx & 255;
            st[row][k] = state[(b0 + row) * 256 + k];
        }
    }
    __syncthreads();

    int gate = tid >> 8, rem = tid & 255;
    int row = rem >> 5, hl = rem & 31;
    int h = h0 + hl;
    int wrow = gate * 256 + h;

    float si = 0.f;
    const float4* wi = (const float4*)(W_ih + (size_t)wrow * 512);
    const float4* gp = (const float4*)(&g[row][0]);
    #pragma unroll 4
    for (int k4 = 0; k4 < 128; ++k4) {
        float4 wv = wi[k4], gv = gp[k4];
        si += wv.x * gv.x + wv.y * gv.y + wv.z * gv.z + wv.w * gv.w;
    }
    float sh = 0.f;
    const float4* wh = (const float4*)(W_hh + (size_t)wrow * 256);
    const float4* sp = (const float4*)(&st[row][0]);
    #pragma unroll 4
    for (int k4 = 0; k4 < 64; ++k4) {
        float4 wv = wh[k4], sv = sp[k4];
        sh += wv.x * sv.x + wv.y * sv.y + wv.z * sv.z + wv.w * sv.w;
    }
    xi[gate * 256 + rem] = si + b_ih[wrow];
    xh[gate * 256 + rem] = sh + b_hh[wrow];
    __syncthreads();

    if (tid < 256) {
        int row2 = tid >> 5, h2 = h0 + (tid & 31);
        float ir = xi[tid],       hr = xh[tid];
        float iz = xi[256 + tid], hz = xh[256 + tid];
        float in_ = xi[512 + tid], hn = xh[512 + tid];
        float r = fast_sigmoid(ir + hr);
        float z = fast_sigmoid(iz + hz);
        float n = fast_tanh(in_ + r * hn);
        out[(b0 + row2) * 256 + h2] = (1.f - z) * n + z * st[row2][h2];
    }
}

extern "C" void kernel_launch(void* const* d_in, const int* in_sizes, int n_in,
                              void* d_out, int out_size, void* d_ws, size_t ws_size,
                              hipStream_t stream) {
    const float* input  = (const float*)d_in[0];
    const float* memory = (const float*)d_in[1];
    const int*   mask   = (const int*)d_in[2];
    const float* state  = (const float*)d_in[3];
    const float* W_a1   = (const float*)d_in[4];
    const float* w_a2   = (const float*)d_in[5];
    const float* W_gate = (const float*)d_in[6];
    const float* W_ih   = (const float*)d_in[7];
    const float* W_hh   = (const float*)d_in[8];
    const float* b_ih   = (const float*)d_in[9];
    const float* b_hh   = (const float*)d_in[10];
    float* out = (float*)d_out;

    char* ws = (char*)d_ws;
    unsigned short* WmT = (unsigned short*)(ws + 0);        // 131072 B
    float* qs     = (float*)(ws + 131072);                  // 65536 B
    float* attn   = (float*)(ws + 196608);                  // 65536 B
    float* gated  = (float*)(ws + 262144);                  // 131072 B
    float* part_m = (float*)(ws + 393216);                  // 8192 B
    float* part_l = (float*)(ws + 401408);                  // 8192 B
    float* part_acc = (float*)(ws + 409600);                // 2097152 B

    prep_wmt<<<256, 256, 0, stream>>>(W_a1, WmT);
    qs_kernel<<<dim3(8, 8), 256, 0, stream>>>(input, state, W_a1, qs);
    attn_kernel<<<dim3(B_DIM, NCH), 512, 0, stream>>>(
        memory, mask, WmT, qs, w_a2, part_m, part_l, part_acc);
    merge_kernel<<<64, 256, 0, stream>>>(part_m, part_l, part_acc, attn);
    gate_kernel<<<dim3(16, 8), 256, 0, stream>>>(input, attn, W_gate, gated);
    gru_kernel<<<dim3(8, 8), 768, 0, stream>>>(gated, state, W_ih, W_hh, b_ih, b_hh, out);
}

// Round 3
// 100.770 us; speedup vs baseline: 1.8602x; 1.8503x over previous
//
#include <hip/hip_runtime.h>
#include <hip/hip_bf16.h>

#define T_DIM 2048
#define B_DIM 64
#define H_DIM 256
#define A_DIM 256
#define NCH 32
#define TCH 64
#define NEG_INF -1e12f

typedef __attribute__((ext_vector_type(8))) short short8;
typedef __attribute__((ext_vector_type(4))) float f32x4;

__device__ __forceinline__ unsigned short bfbits(float f) {
    __hip_bfloat16 h = __float2bfloat16(f);
    unsigned short u;
    __builtin_memcpy(&u, &h, 2);
    return u;
}
__device__ __forceinline__ float fast_tanh(float x) {
    float e = __expf(2.0f * x);
    return 1.0f - 2.0f / (e + 1.0f);
}
__device__ __forceinline__ float fast_sigmoid(float x) {
    return 1.0f / (1.0f + __expf(-x));
}

// K0: fused WmT prep (blocks 0..255) + qs GEMV (blocks 256..319)
__global__ void prep_qs_kernel(const float* __restrict__ W_a1,
                               const float* __restrict__ input,
                               const float* __restrict__ state,
                               unsigned short* __restrict__ WmT,
                               float* __restrict__ qs) {
    __shared__ float cat[512];
    int bid = blockIdx.x, tid = threadIdx.x;
    if (bid < 256) {
        // WmT[a][k] = bf16(W_a1[512+k][a]); k = bid, a = tid (coalesced read)
        WmT[tid * 256 + bid] = bfbits(W_a1[(512 + bid) * 256 + tid]);
    } else {
        int b = bid - 256;
        cat[tid] = input[b * 256 + tid];
        cat[256 + tid] = state[b * 256 + tid];
        __syncthreads();
        int a = tid;
        float s0 = 0.f, s1 = 0.f, s2 = 0.f, s3 = 0.f;
        #pragma unroll 4
        for (int k = 0; k < 512; k += 4) {
            s0 += cat[k]     * W_a1[(k)     * 256 + a];
            s1 += cat[k + 1] * W_a1[(k + 1) * 256 + a];
            s2 += cat[k + 2] * W_a1[(k + 2) * 256 + a];
            s3 += cat[k + 3] * W_a1[(k + 3) * 256 + a];
        }
        qs[b * 256 + a] = (s0 + s1) + (s2 + s3);
    }
}

// K1: fused logits-MLP (swapped-operand MFMA: C[a][t]) + chunk softmax + PV.
// grid (B, NCH), block 512 (8 waves); wave w owns a-range [w*32, w*32+32).
__global__ __launch_bounds__(512, 2) void attn_kernel(
    const float* __restrict__ memory, const int* __restrict__ mask,
    const unsigned short* __restrict__ WmT,
    const float* __restrict__ qs, const float* __restrict__ w_a2,
    float* __restrict__ part_m, float* __restrict__ part_l,
    float* __restrict__ part_acc)
{
    __shared__ unsigned short slab[TCH * 256];   // 32 KB, [t][k] bf16, XOR-swizzled
    __shared__ float acc2[16 * 256];             // 16 KB PV partials
    __shared__ float lpart[8 * 64];
    __shared__ float pbuf[TCH];
    __shared__ float redm[2];

    int b = blockIdx.x, ch = blockIdx.y;
    int tid = threadIdx.x;
    int lane = tid & 63, w = tid >> 6;
    int lr = lane & 15, lh = lane >> 4;
    int t0 = ch * TCH;
    const float* mbase = memory + (size_t)t0 * (B_DIM * H_DIM) + b * H_DIM;

    // per-lane epilogue constants: 8 a-values (C rows) per lane
    int wa0 = w * 32;
    float qv[2][4], wv[2][4];
    #pragma unroll
    for (int mf = 0; mf < 2; ++mf)
        #pragma unroll
        for (int r = 0; r < 4; ++r) {
            int a = wa0 + mf * 16 + lh * 4 + r;
            qv[mf][r] = qs[b * 256 + a];
            wv[mf][r] = w_a2[a];
        }

    // ---- stage slab: f32 -> bf16 (HW cvt_pk), swizzle byte ^= ((t&7)<<4) ----
    #pragma unroll
    for (int i = 0; i < 8; ++i) {
        int idx4 = i * 512 + tid;
        int t = idx4 >> 6, h4 = idx4 & 63;
        const float4* rp = (const float4*)(mbase + (size_t)t * (B_DIM * H_DIM));
        float4 v = rp[h4];
        ushort4 o;
        o.x = bfbits(v.x); o.y = bfbits(v.y); o.z = bfbits(v.z); o.w = bfbits(v.w);
        int sw = ((h4 * 8) ^ ((t & 7) << 4)) >> 1;
        *(ushort4*)(slab + t * 256 + sw) = o;
    }
    __syncthreads();

    // ---- MFMA: C[a_local][t_local] = sum_k WmT[a][k] * slab[t][k] ----
    f32x4 acc[2][4];
    #pragma unroll
    for (int mf = 0; mf < 2; ++mf)
        #pragma unroll
        for (int nf = 0; nf < 4; ++nf)
            acc[mf][nf] = (f32x4){0.f, 0.f, 0.f, 0.f};

    #pragma unroll
    for (int kk = 0; kk < 8; ++kk) {
        short8 afr[2];                            // A = WmT rows (a), k-contig
        #pragma unroll
        for (int mf = 0; mf < 2; ++mf) {
            int a = wa0 + mf * 16 + lr;
            afr[mf] = *(const short8*)(WmT + a * 256 + kk * 32 + lh * 8);
        }
        int kbyte = kk * 64 + lh * 16;
        #pragma unroll
        for (int nf = 0; nf < 4; ++nf) {          // B = slab rows (t), k-contig
            int t = nf * 16 + lr;
            int sw = kbyte ^ ((t & 7) << 4);
            short8 bfr = *(const short8*)(slab + t * 256 + (sw >> 1));
            #pragma unroll
            for (int mf = 0; mf < 2; ++mf)
                acc[mf][nf] = __builtin_amdgcn_mfma_f32_16x16x32_bf16(afr[mf], bfr, acc[mf][nf], 0, 0, 0);
        }
    }

    // ---- epilogue: per-lane in-register reduce over a, 2 shuffles over lh ----
    #pragma unroll
    for (int nf = 0; nf < 4; ++nf) {
        float s = 0.f;
        #pragma unroll
        for (int mf = 0; mf < 2; ++mf)
            #pragma unroll
            for (int r = 0; r < 4; ++r)
                s += wv[mf][r] * fast_tanh(qv[mf][r] + acc[mf][nf][r]);
        s += __shfl_xor(s, 16);
        s += __shfl_xor(s, 32);
        if (lh == 0) lpart[w * 64 + nf * 16 + lr] = s;
    }
    __syncthreads();

    // ---- combine 8 wave partials, mask ----
    if (tid < 64) {
        float lg = 0.f;
        #pragma unroll
        for (int ww = 0; ww < 8; ++ww) lg += lpart[ww * 64 + tid];
        int t = t0 + tid;
        pbuf[tid] = mask[t * B_DIM + b] ? lg : NEG_INF;
    }
    __syncthreads();

    // ---- chunk-local softmax (wave 0, one t per lane) ----
    if (w == 0) {
        float a0 = pbuf[lane];
        float mx = a0;
        #pragma unroll
        for (int d = 1; d < 64; d <<= 1) mx = fmaxf(mx, __shfl_xor(mx, d));
        float e0 = __expf(a0 - mx);
        float sm = e0;
        #pragma unroll
        for (int d = 1; d < 64; d <<= 1) sm += __shfl_xor(sm, d);
        pbuf[lane] = e0;
        if (lane == 0) { redm[0] = mx; redm[1] = sm; }
    }
    __syncthreads();

    // ---- PV: vectorized b128 reads; thread = (h-oct, t-slice of 4) ----
    int oct = tid & 31, slice = tid >> 5;
    int h0 = oct * 8;
    float a8[8] = {0.f, 0.f, 0.f, 0.f, 0.f, 0.f, 0.f, 0.f};
    #pragma unroll
    for (int tt = 0; tt < 4; ++tt) {
        int t = slice * 4 + tt;
        float pt = pbuf[t];
        int swb = (h0 * 2) ^ ((t & 7) << 4);
        uint4 u = *(const uint4*)(slab + t * 256 + (swb >> 1));
        a8[0] += pt * __uint_as_float(u.x << 16);
        a8[1] += pt * __uint_as_float(u.x & 0xFFFF0000u);
        a8[2] += pt * __uint_as_float(u.y << 16);
        a8[3] += pt * __uint_as_float(u.y & 0xFFFF0000u);
        a8[4] += pt * __uint_as_float(u.z << 16);
        a8[5] += pt * __uint_as_float(u.z & 0xFFFF0000u);
        a8[6] += pt * __uint_as_float(u.w << 16);
        a8[7] += pt * __uint_as_float(u.w & 0xFFFF0000u);
    }
    *(float4*)(&acc2[slice * 256 + h0])     = (float4){a8[0], a8[1], a8[2], a8[3]};
    *(float4*)(&acc2[slice * 256 + h0 + 4]) = (float4){a8[4], a8[5], a8[6], a8[7]};
    __syncthreads();
    int pidx = ch * B_DIM + b;
    if (tid < 256) {
        float s = 0.f;
        #pragma unroll
        for (int sl = 0; sl < 16; ++sl) s += acc2[sl * 256 + tid];
        part_acc[(size_t)pidx * 256 + tid] = s;
    }
    if (tid == 0) { part_m[pidx] = redm[0]; part_l[pidx] = redm[1]; }
}

// K2: fused merge (chunk-partials -> attn row) + gate GEMV. block = one b.
__global__ void mergegate_kernel(const float* __restrict__ part_m,
                                 const float* __restrict__ part_l,
                                 const float* __restrict__ part_acc,
                                 const float* __restrict__ input,
                                 const float* __restrict__ W_gate,
                                 float* __restrict__ gated) {
    __shared__ float ni[512];
    int b = blockIdx.x, tid = threadIdx.x;
    if (tid >= 256) {
        int k = tid - 256;
        ni[k] = input[b * 256 + k];
    } else {
        int h = tid;
        float M = -3.4e38f;
        #pragma unroll
        for (int c = 0; c < NCH; ++c) M = fmaxf(M, part_m[c * 64 + b]);
        float L = 0.f, s = 0.f;
        #pragma unroll 4
        for (int c = 0; c < NCH; ++c) {
            float sc = __expf(part_m[c * 64 + b] - M);
            L += part_l[c * 64 + b] * sc;
            s += sc * part_acc[(size_t)(c * 64 + b) * 256 + h];
        }
        ni[256 + h] = s / L;
    }
    __syncthreads();
    int j = tid;
    float s0 = 0.f, s1 = 0.f, s2 = 0.f, s3 = 0.f;
    #pragma unroll 4
    for (int k = 0; k < 512; k += 4) {
        s0 += ni[k]     * W_gate[(k)     * 512 + j];
        s1 += ni[k + 1] * W_gate[(k + 1) * 512 + j];
        s2 += ni[k + 2] * W_gate[(k + 2) * 512 + j];
        s3 += ni[k + 3] * W_gate[(k + 3) * 512 + j];
    }
    float s = (s0 + s1) + (s2 + s3);
    gated[b * 512 + j] = ni[j] * fast_sigmoid(s);
}

// K3: GRU cell, one kernel. grid 256 = (16 b-tiles x 16 h-tiles), block 768.
// 48 groups of 16 lanes: group = (gate 0..2, hl 0..15); lanes cover k
// (coalesced weight rows, register-cached); in-block gate combine.
__global__ __launch_bounds__(768) void gru_kernel(
    const float* __restrict__ gated, const float* __restrict__ state,
    const float* __restrict__ W_ih, const float* __restrict__ W_hh,
    const float* __restrict__ b_ih, const float* __restrict__ b_hh,
    float* __restrict__ out) {
    __shared__ float ld_g[4][512];
    __shared__ float ld_s[4][256];
    __shared__ float xi[3][16][4];
    __shared__ float xh[3][16][4];
    int ht = blockIdx.x & 15, bt = blockIdx.x >> 4;
    int tid = threadIdx.x;
    #pragma unroll
    for (int i = 0; i < 3; ++i) {
        int idx = i * 768 + tid;
        if (idx < 2048) ld_g[idx >> 9][idx & 511] = gated[(bt * 4 + (idx >> 9)) * 512 + (idx & 511)];
    }
    #pragma unroll
    for (int i = 0; i < 2; ++i) {
        int idx = i * 768 + tid;
        if (idx < 1024) ld_s[idx >> 8][idx & 255] = state[(bt * 4 + (idx >> 8)) * 256 + (idx & 255)];
    }

    int gid = tid >> 4, lk = tid & 15;
    int gate = gid >> 4, hl = gid & 15;
    int j = gate * 256 + ht * 16 + hl;

    float4 wi[8], wh[4];
    #pragma unroll
    for (int it = 0; it < 8; ++it)
        wi[it] = *(const float4*)(W_ih + (size_t)j * 512 + it * 64 + lk * 4);
    #pragma unroll
    for (int it = 0; it < 4; ++it)
        wh[it] = *(const float4*)(W_hh + (size_t)j * 256 + it * 64 + lk * 4);
    float bi = b_ih[j], bh = b_hh[j];
    __syncthreads();

    #pragma unroll
    for (int bb = 0; bb < 4; ++bb) {
        float g0 = 0.f, g1 = 0.f;
        #pragma unroll
        for (int it = 0; it < 8; ++it) {
            float4 gv = *(const float4*)(&ld_g[bb][it * 64 + lk * 4]);
            g0 += wi[it].x * gv.x + wi[it].z * gv.z;
            g1 += wi[it].y * gv.y + wi[it].w * gv.w;
        }
        float h0 = 0.f, h1 = 0.f;
        #pragma unroll
        for (int it = 0; it < 4; ++it) {
            float4 sv = *(const float4*)(&ld_s[bb][it * 64 + lk * 4]);
            h0 += wh[it].x * sv.x + wh[it].z * sv.z;
            h1 += wh[it].y * sv.y + wh[it].w * sv.w;
        }
        float gi_ = g0 + g1, gh_ = h0 + h1;
        #pragma unroll
        for (int m = 1; m < 16; m <<= 1) {
            gi_ += __shfl_xor(gi_, m);
            gh_ += __shfl_xor(gh_, m);
        }
        if (lk == 0) { xi[gate][hl][bb] = gi_ + bi; xh[gate][hl][bb] = gh_ + bh; }
    }
    __syncthreads();
    if (tid < 64) {
        int bb = tid >> 4, hl2 = tid & 15;
        float ir = xi[0][hl2][bb], hr = xh[0][hl2][bb];
        float iz = xi[1][hl2][bb], hz = xh[1][hl2][bb];
        float in_ = xi[2][hl2][bb], hn = xh[2][hl2][bb];
        float r = fast_sigmoid(ir + hr);
        float z = fast_sigmoid(iz + hz);
        float n = fast_tanh(in_ + r * hn);
        out[(bt * 4 + bb) * 256 + ht * 16 + hl2] =
            (1.f - z) * n + z * ld_s[bb][ht * 16 + hl2];
    }
}

extern "C" void kernel_launch(void* const* d_in, const int* in_sizes, int n_in,
                              void* d_out, int out_size, void* d_ws, size_t ws_size,
                              hipStream_t stream) {
    const float* input  = (const float*)d_in[0];
    const float* memory = (const float*)d_in[1];
    const int*   mask   = (const int*)d_in[2];
    const float* state  = (const float*)d_in[3];
    const float* W_a1   = (const float*)d_in[4];
    const float* w_a2   = (const float*)d_in[5];
    const float* W_gate = (const float*)d_in[6];
    const float* W_ih   = (const float*)d_in[7];
    const float* W_hh   = (const float*)d_in[8];
    const float* b_ih   = (const float*)d_in[9];
    const float* b_hh   = (const float*)d_in[10];
    float* out = (float*)d_out;

    char* ws = (char*)d_ws;
    unsigned short* WmT = (unsigned short*)(ws + 0);        // 131072 B
    float* qs       = (float*)(ws + 131072);                // 65536 B
    float* gated    = (float*)(ws + 196608);                // 131072 B
    float* part_m   = (float*)(ws + 327680);                // 8192 B
    float* part_l   = (float*)(ws + 335872);                // 8192 B
    float* part_acc = (float*)(ws + 344064);                // 2097152 B

    prep_qs_kernel<<<320, 256, 0, stream>>>(W_a1, input, state, WmT, qs);
    attn_kernel<<<dim3(B_DIM, NCH), 512, 0, stream>>>(
        memory, mask, WmT, qs, w_a2, part_m, part_l, part_acc);
    mergegate_kernel<<<64, 512, 0, stream>>>(part_m, part_l, part_acc, input, W_gate, gated);
    gru_kernel<<<256, 768, 0, stream>>>(gated, state, W_ih, W_hh, b_ih, b_hh, out);
}